// Round 7
// baseline (133.533 us; speedup 1.0000x reference)
//
#include <hip/hip_runtime.h>
#include <math.h>

#define NN_ 256      // nodes per graph
#define BB_ 64       // batch
#define FF_ 5        // features
#define NE_ 65536    // NN_*NN_

// workspace layout in floats (~1 MB, L2/L3-resident)
// Operators stored DE-NORMALIZED and transposed: Op[k*256+j] = pure weight
//   SLA = w, SL1 = z0*w, SL3 = z1*w, SL5 = z2*w   (no dis, no 0.45, no diag)
// Chain applies  y_j = 0.1*x_j + 0.45*dis_j * sum_k Op[k,j]*(dis_k*x_k).
#define OFF_SLA 0        // pure w
#define OFF_SL1 65536    // z0*w
#define OFF_SL3 131072   // z1*w
#define OFF_SL5 196608   // z2*w
#define OFF_DIS 262144   // 256 floats

// ---------------------------------------------------------------------------
// K1: fused build (round-1/4 known-good: 256 blocks x 256 threads).
// Block i = operator row i. One p-row gather serves BOTH the deg reduction
// (dis_i) and the four operator writes. Block 0 lanes 0..2 emit the scalar
// tail (kld_loss, drop_rates).
// ---------------------------------------------------------------------------
__global__ __launch_bounds__(256) void build_all(
    const float* __restrict__ p, const float* __restrict__ u_rb,
    const float* __restrict__ a_uc, const float* __restrict__ b_uc,
    const float* __restrict__ u_pi, float* __restrict__ ws,
    float* __restrict__ out) {
  const int i = blockIdx.x, j = threadIdx.x;
  const int t = (i >= j) ? (i * (i + 1) / 2 + j) : (j * (j + 1) / 2 + i);
  const float w = p[t];

  __shared__ float sh[NN_];
  __shared__ float slg[3];
  __shared__ float skld[3];
  sh[j] = fabsf(w);

  if (j < 3) {
    const int l = j;
    const float au = fmaxf(a_uc[l], -10.0f);
    const float bu = fminf(fmaxf(b_uc[l], -10.0f), 50.0f);
    const float a = log1pf(expf(au));
    const float b = log1pf(expf(bu));
    const float up = fminf(fmaxf(u_pi[l], 1e-6f), 1.0f - 1e-6f);
    const float pi = powf(1.0f - powf(up, 1.0f / b), 1.0f / a);
    slg[l] = logf(pi) - log1pf(-pi);
    if (i == 0) {
      out[193 + l] = pi;  // drop_rates
      float x = b, dg = 0.0f;
      while (x < 6.0f) { dg -= 1.0f / x; x += 1.0f; }
      const float inv = 1.0f / x, inv2 = inv * inv;
      dg += logf(x) - 0.5f * inv
            - inv2 * (1.0f / 12.0f - inv2 * (1.0f / 120.0f - inv2 * (1.0f / 252.0f)));
      const float euler = 0.577215664901532f;
      skld[l] = (1.0f - 0.8f / a) * (-euler - dg - 1.0f / b)
                + logf(a * b + 1e-10f) - logf(0.8f) - (b - 1.0f) / b;
    }
  }
  __syncthreads();

  // deg_i = sum_j |W[i,j]| via LDS tree reduction over the row we just loaded
  for (int s = NN_ / 2; s > 0; s >>= 1) {
    if (j < s) sh[j] += sh[j + s];
    __syncthreads();
  }
  if (j == 0) {
    const float deg = sh[0];
    ws[OFF_DIS + i] = (deg > 0.0f) ? (1.0f / sqrtf(deg)) : 0.0f;
    if (i == 0) out[192] = skld[0] + skld[1] + skld[2];  // kld_loss
  }

  // pure (un-normalized) operators; coalesced u_rb reads and ws writes
  const float lg0 = slg[0];
  const float lg1 = slg[1];
  const float lg2 = slg[2];
  const int idx = i * NN_ + j;
  const float inv_temp = 1.0f / 0.6f;

  ws[OFF_SLA + idx] = w;

  float u, v;
  u = fminf(fmaxf(u_rb[0 * NE_ + idx], 1e-6f), 1.0f - 1e-6f);
  v = (lg0 + logf(u) - log1pf(-u)) * inv_temp;
  ws[OFF_SL1 + idx] = w / (1.0f + expf(-v));

  u = fminf(fmaxf(u_rb[1 * NE_ + idx], 1e-6f), 1.0f - 1e-6f);
  v = (lg1 + logf(u) - log1pf(-u)) * inv_temp;
  ws[OFF_SL3 + idx] = w / (1.0f + expf(-v));

  u = fminf(fmaxf(u_rb[2 * NE_ + idx], 1e-6f), 1.0f - 1e-6f);
  v = (lg2 + logf(u) - log1pf(-u)) * inv_temp;
  ws[OFF_SL5 + idx] = w / (1.0f + expf(-v));
}

// ---------------------------------------------------------------------------
// K2: per-batch chain (round-4 structure, vmem halved). 64 blocks x 1024
// threads. X and S = dis*X in LDS ping-pong. Each thread computes TWO
// ADJACENT j-columns (2*jg, 2*jg+1) so the two operator reads fuse into ONE
// float2 load (global_load_dwordx2, 512 contiguous B per wave) -> vmem
// wave-instrs per CU per stage drop 1024 -> 512. k-axis split 8 ways;
// 8 partial sets (64 KB) combined per stage. Total LDS 97.25 KB.
// ---------------------------------------------------------------------------
__global__ __launch_bounds__(1024) void batch_chain(
    const float* __restrict__ x0g, const float* __restrict__ ws,
    const float* __restrict__ lin_w, const float* __restrict__ lin_b,
    const float* __restrict__ fc_w, const float* __restrict__ fc_b,
    float* __restrict__ out) {
  const int b = blockIdx.x, tid = threadIdx.x;
  __shared__ float xbuf[2][NN_ * 8];   // X (unscaled), 16 KB
  __shared__ float sbuf[2][NN_ * 8];   // S = dis*X,    16 KB
  __shared__ float part[8 * NN_ * 8];  // 64 KB: [kq][j][f] (reused by head)
  __shared__ float sdis[NN_];          // 1 KB
  float* Xc = xbuf[0];
  float* Xn = xbuf[1];
  float* Sc = sbuf[0];
  float* Sn = sbuf[1];

  for (int ii = tid; ii < NN_; ii += 1024) sdis[ii] = ws[OFF_DIS + ii];
  // stage input x[b] (layout [b*256+i][5]) into padded LDS rows [i][8]
  for (int idx = tid; idx < NN_ * FF_; idx += 1024) {
    const int i = idx / 5, f = idx - 5 * i;
    Xc[i * 8 + f] = x0g[b * (NN_ * FF_) + idx];
  }
  __syncthreads();
  for (int idx = tid; idx < 2048; idx += 1024)
    Sc[idx] = sdis[idx >> 3] * Xc[idx];   // pad lanes garbage, never read
  __syncthreads();

  const int q = tid >> 7;       // k-eighth 0..7
  const int jg = tid & 127;     // j-pair index: columns 2*jg, 2*jg+1
  const int k0 = q * 32;

#pragma unroll
  for (int l = 0; l < 5; ++l) {
    const float* __restrict__ Op =
        ws + (l == 0 ? OFF_SL1 : l == 2 ? OFF_SL3 : l == 4 ? OFF_SL5 : OFF_SLA)
        + 2 * jg;
    float4 p03 = {0.f, 0.f, 0.f, 0.f};
    float4 r03 = {0.f, 0.f, 0.f, 0.f};
    float p4 = 0.f, r4 = 0.f;
#pragma unroll 8
    for (int k = k0; k < k0 + 32; ++k) {
      const float2 w01 = *(const float2*)(Op + k * NN_);  // ONE dwordx2 load
      const float4 xv = *(const float4*)(Sc + k * 8);     // LDS broadcast
      const float x4 = Sc[k * 8 + 4];                     // LDS broadcast
      p03.x += w01.x * xv.x; p03.y += w01.x * xv.y;
      p03.z += w01.x * xv.z; p03.w += w01.x * xv.w; p4 += w01.x * x4;
      r03.x += w01.y * xv.x; r03.y += w01.y * xv.y;
      r03.z += w01.y * xv.z; r03.w += w01.y * xv.w; r4 += w01.y * x4;
    }
    // part[q][j][0..4]; pads f=5..7 garbage, feed only pad lanes
    float* const pp0 = part + (q * NN_ + 2 * jg) * 8;
    float* const pp1 = pp0 + 8;
    *(float4*)pp0 = p03; pp0[4] = p4;
    *(float4*)pp1 = r03; pp1[4] = r4;
    __syncthreads();
    // combine 8 k-eighths: 2048 padded entries
    for (int idx = tid; idx < 2048; idx += 1024) {
      float sum = part[idx];
#pragma unroll
      for (int qq = 1; qq < 8; ++qq) sum += part[qq * 2048 + idx];
      const float dj = sdis[idx >> 3];
      float y = 0.1f * Xc[idx] + 0.45f * dj * sum;
      if (l == 2) y = fmaxf(y, 0.f);
      Xn[idx] = y;
      Sn[idx] = dj * y;
    }
    __syncthreads();
    float* tp = Xc; Xc = Xn; Xn = tp;
    tp = Sc; Sc = Sn; Sn = tp;
  }

  // head: Xc holds O (256 x 5, padded 8). relu(O@lin_w+lin_b) -> pool -> fc.
  const int k = tid & 127, seg = tid >> 7;  // 8 segs x 32 rows
  const float lw0 = lin_w[0 * 128 + k];
  const float lw1 = lin_w[1 * 128 + k];
  const float lw2 = lin_w[2 * 128 + k];
  const float lw3 = lin_w[3 * 128 + k];
  const float lw4 = lin_w[4 * 128 + k];
  const float lb = lin_b[k];
  float acc = 0.f;
  const int r0 = seg * 32;
#pragma unroll 4
  for (int jj = r0; jj < r0 + 32; ++jj) {
    const float4 ov = *(const float4*)(Xc + jj * 8);  // LDS broadcast
    const float o4 = Xc[jj * 8 + 4];
    const float vv = lb + lw0 * ov.x + lw1 * ov.y + lw2 * ov.z +
                     lw3 * ov.w + lw4 * o4;
    acc += fmaxf(vv, 0.f);
  }
  part[seg * 128 + k] = acc;
  __syncthreads();
  if (tid < 128) {
    float s = 0.f;
#pragma unroll
    for (int s8 = 0; s8 < 8; ++s8) s += part[s8 * 128 + tid];
    part[tid] = s;  // pooled[k]
  }
  __syncthreads();
  if (tid < 3) {
    float s = fc_b[tid];
    for (int kk = 0; kk < 128; ++kk) s += part[kk] * fc_w[kk * 3 + tid];
    out[b * 3 + tid] = s;
  }
}

// ---------------------------------------------------------------------------
extern "C" void kernel_launch(void* const* d_in, const int* in_sizes, int n_in,
                              void* d_out, int out_size, void* d_ws,
                              size_t ws_size, hipStream_t stream) {
  const float* x      = (const float*)d_in[0];
  const float* p      = (const float*)d_in[1];
  const float* a_uc   = (const float*)d_in[2];
  const float* b_uc   = (const float*)d_in[3];
  const float* u_pi   = (const float*)d_in[4];
  const float* u_rb   = (const float*)d_in[5];
  const float* lin_w  = (const float*)d_in[6];
  const float* lin_b  = (const float*)d_in[7];
  const float* fc_w   = (const float*)d_in[8];
  const float* fc_b   = (const float*)d_in[9];
  // d_in[10] edge_index, d_in[11] batch: fully deterministic, never read.
  float* out = (float*)d_out;
  float* ws  = (float*)d_ws;

  build_all<<<256, 256, 0, stream>>>(p, u_rb, a_uc, b_uc, u_pi, ws, out);
  batch_chain<<<64, 1024, 0, stream>>>(x, ws, lin_w, lin_b, fc_w, fc_b, out);
}

// Round 8
// 126.372 us; speedup vs baseline: 1.0567x; 1.0567x over previous
//
#include <hip/hip_runtime.h>
#include <math.h>

#define NN_ 256      // nodes per graph
#define BB_ 64       // batch
#define FF_ 5        // features
#define NE_ 65536    // NN_*NN_

// workspace layout in floats (~1 MB, L2/L3-resident)
// Operators stored DE-NORMALIZED and transposed: Op[k*256+j] = pure weight
//   SLA = w, SL1 = z0*w, SL3 = z1*w, SL5 = z2*w   (no dis, no 0.45, no diag)
// Chain applies  y_j = 0.1*x_j + 0.45*dis_j * sum_k Op[k,j]*(dis_k*x_k).
#define OFF_SLA 0        // pure w
#define OFF_SL1 65536    // z0*w
#define OFF_SL3 131072   // z1*w
#define OFF_SL5 196608   // z2*w
#define OFF_DIS 262144   // 256 floats

// ---------------------------------------------------------------------------
// K1: fused build (round-1 known-good: 256 blocks x 256 threads).
// Block i = operator row i. One p-row gather serves BOTH the deg reduction
// (dis_i) and the four operator writes. Block 0 lanes 0..2 emit the scalar
// tail (kld_loss, drop_rates).
// ---------------------------------------------------------------------------
__global__ __launch_bounds__(256) void build_all(
    const float* __restrict__ p, const float* __restrict__ u_rb,
    const float* __restrict__ a_uc, const float* __restrict__ b_uc,
    const float* __restrict__ u_pi, float* __restrict__ ws,
    float* __restrict__ out) {
  const int i = blockIdx.x, j = threadIdx.x;
  const int t = (i >= j) ? (i * (i + 1) / 2 + j) : (j * (j + 1) / 2 + i);
  const float w = p[t];

  __shared__ float sh[NN_];
  __shared__ float slg[3];
  __shared__ float skld[3];
  sh[j] = fabsf(w);

  if (j < 3) {
    const int l = j;
    const float au = fmaxf(a_uc[l], -10.0f);
    const float bu = fminf(fmaxf(b_uc[l], -10.0f), 50.0f);
    const float a = log1pf(expf(au));
    const float b = log1pf(expf(bu));
    const float up = fminf(fmaxf(u_pi[l], 1e-6f), 1.0f - 1e-6f);
    const float pi = powf(1.0f - powf(up, 1.0f / b), 1.0f / a);
    slg[l] = logf(pi) - log1pf(-pi);
    if (i == 0) {
      out[193 + l] = pi;  // drop_rates
      float x = b, dg = 0.0f;
      while (x < 6.0f) { dg -= 1.0f / x; x += 1.0f; }
      const float inv = 1.0f / x, inv2 = inv * inv;
      dg += logf(x) - 0.5f * inv
            - inv2 * (1.0f / 12.0f - inv2 * (1.0f / 120.0f - inv2 * (1.0f / 252.0f)));
      const float euler = 0.577215664901532f;
      skld[l] = (1.0f - 0.8f / a) * (-euler - dg - 1.0f / b)
                + logf(a * b + 1e-10f) - logf(0.8f) - (b - 1.0f) / b;
    }
  }
  __syncthreads();

  // deg_i = sum_j |W[i,j]| via LDS tree reduction over the row we just loaded
  for (int s = NN_ / 2; s > 0; s >>= 1) {
    if (j < s) sh[j] += sh[j + s];
    __syncthreads();
  }
  if (j == 0) {
    const float deg = sh[0];
    ws[OFF_DIS + i] = (deg > 0.0f) ? (1.0f / sqrtf(deg)) : 0.0f;
    if (i == 0) out[192] = skld[0] + skld[1] + skld[2];  // kld_loss
  }

  // pure (un-normalized) operators; coalesced u_rb reads and ws writes
  const float lg0 = slg[0];
  const float lg1 = slg[1];
  const float lg2 = slg[2];
  const int idx = i * NN_ + j;
  const float inv_temp = 1.0f / 0.6f;

  ws[OFF_SLA + idx] = w;

  float u, v;
  u = fminf(fmaxf(u_rb[0 * NE_ + idx], 1e-6f), 1.0f - 1e-6f);
  v = (lg0 + logf(u) - log1pf(-u)) * inv_temp;
  ws[OFF_SL1 + idx] = w / (1.0f + expf(-v));

  u = fminf(fmaxf(u_rb[1 * NE_ + idx], 1e-6f), 1.0f - 1e-6f);
  v = (lg1 + logf(u) - log1pf(-u)) * inv_temp;
  ws[OFF_SL3 + idx] = w / (1.0f + expf(-v));

  u = fminf(fmaxf(u_rb[2 * NE_ + idx], 1e-6f), 1.0f - 1e-6f);
  v = (lg2 + logf(u) - log1pf(-u)) * inv_temp;
  ws[OFF_SL5 + idx] = w / (1.0f + expf(-v));
}

// ---------------------------------------------------------------------------
// K2: per-batch chain. 64 blocks x 1024 threads. X and S = dis*X in LDS
// ping-pong. Each thread computes TWO j-columns (j0, j0+128) sharing one
// broadcast pair per k-row; k-axis split 8 ways (32 k per thread); 8 partial
// sets (64 KB) combined per stage. Total static LDS 97.25 KB.
// Measured best config of the session (126.6 us total).
// ---------------------------------------------------------------------------
__global__ __launch_bounds__(1024) void batch_chain(
    const float* __restrict__ x0g, const float* __restrict__ ws,
    const float* __restrict__ lin_w, const float* __restrict__ lin_b,
    const float* __restrict__ fc_w, const float* __restrict__ fc_b,
    float* __restrict__ out) {
  const int b = blockIdx.x, tid = threadIdx.x;
  __shared__ float xbuf[2][NN_ * 8];   // X (unscaled), 16 KB
  __shared__ float sbuf[2][NN_ * 8];   // S = dis*X,    16 KB
  __shared__ float part[8 * NN_ * 8];  // 64 KB: [kq][j][f] (reused by head)
  __shared__ float sdis[NN_];          // 1 KB
  float* Xc = xbuf[0];
  float* Xn = xbuf[1];
  float* Sc = sbuf[0];
  float* Sn = sbuf[1];

  for (int ii = tid; ii < NN_; ii += 1024) sdis[ii] = ws[OFF_DIS + ii];
  // stage input x[b] (layout [b*256+i][5]) into padded LDS rows [i][8]
  for (int idx = tid; idx < NN_ * FF_; idx += 1024) {
    const int i = idx / 5, f = idx - 5 * i;
    Xc[i * 8 + f] = x0g[b * (NN_ * FF_) + idx];
  }
  __syncthreads();
  for (int idx = tid; idx < 2048; idx += 1024)
    Sc[idx] = sdis[idx >> 3] * Xc[idx];   // pad lanes garbage, never read
  __syncthreads();

  const int q = tid >> 7;       // k-eighth 0..7
  const int j0 = tid & 127;     // first output node (second = j0+128)
  const int k0 = q * 32;

#pragma unroll
  for (int l = 0; l < 5; ++l) {
    const float* __restrict__ Op =
        ws + (l == 0 ? OFF_SL1 : l == 2 ? OFF_SL3 : l == 4 ? OFF_SL5 : OFF_SLA)
        + j0;
    float4 p03 = {0.f, 0.f, 0.f, 0.f};
    float4 r03 = {0.f, 0.f, 0.f, 0.f};
    float p4 = 0.f, r4 = 0.f;
#pragma unroll 8
    for (int k = k0; k < k0 + 32; ++k) {
      const float w0 = Op[k * NN_];                     // coalesced (L2)
      const float w1 = Op[k * NN_ + 128];               // coalesced (L2)
      const float4 xv = *(const float4*)(Sc + k * 8);   // LDS broadcast
      const float x4 = Sc[k * 8 + 4];                   // LDS broadcast
      p03.x += w0 * xv.x; p03.y += w0 * xv.y;
      p03.z += w0 * xv.z; p03.w += w0 * xv.w; p4 += w0 * x4;
      r03.x += w1 * xv.x; r03.y += w1 * xv.y;
      r03.z += w1 * xv.z; r03.w += w1 * xv.w; r4 += w1 * x4;
    }
    // part[q][j][0..4]; pads f=5..7 garbage, feed only pad lanes
    float* const pp0 = part + (q * NN_ + j0) * 8;
    float* const pp1 = part + (q * NN_ + j0 + 128) * 8;
    *(float4*)pp0 = p03; pp0[4] = p4;
    *(float4*)pp1 = r03; pp1[4] = r4;
    __syncthreads();
    // combine 8 k-eighths: 2048 padded entries
    for (int idx = tid; idx < 2048; idx += 1024) {
      float sum = part[idx];
#pragma unroll
      for (int qq = 1; qq < 8; ++qq) sum += part[qq * 2048 + idx];
      const float dj = sdis[idx >> 3];
      float y = 0.1f * Xc[idx] + 0.45f * dj * sum;
      if (l == 2) y = fmaxf(y, 0.f);
      Xn[idx] = y;
      Sn[idx] = dj * y;
    }
    __syncthreads();
    float* tp = Xc; Xc = Xn; Xn = tp;
    tp = Sc; Sc = Sn; Sn = tp;
  }

  // head: Xc holds O (256 x 5, padded 8). relu(O@lin_w+lin_b) -> pool -> fc.
  const int k = tid & 127, seg = tid >> 7;  // 8 segs x 32 rows
  const float lw0 = lin_w[0 * 128 + k];
  const float lw1 = lin_w[1 * 128 + k];
  const float lw2 = lin_w[2 * 128 + k];
  const float lw3 = lin_w[3 * 128 + k];
  const float lw4 = lin_w[4 * 128 + k];
  const float lb = lin_b[k];
  float acc = 0.f;
  const int r0 = seg * 32;
#pragma unroll 4
  for (int jj = r0; jj < r0 + 32; ++jj) {
    const float4 ov = *(const float4*)(Xc + jj * 8);  // LDS broadcast
    const float o4 = Xc[jj * 8 + 4];
    const float vv = lb + lw0 * ov.x + lw1 * ov.y + lw2 * ov.z +
                     lw3 * ov.w + lw4 * o4;
    acc += fmaxf(vv, 0.f);
  }
  part[seg * 128 + k] = acc;
  __syncthreads();
  if (tid < 128) {
    float s = 0.f;
#pragma unroll
    for (int s8 = 0; s8 < 8; ++s8) s += part[s8 * 128 + tid];
    part[tid] = s;  // pooled[k]
  }
  __syncthreads();
  if (tid < 3) {
    float s = fc_b[tid];
    for (int kk = 0; kk < 128; ++kk) s += part[kk] * fc_w[kk * 3 + tid];
    out[b * 3 + tid] = s;
  }
}

// ---------------------------------------------------------------------------
extern "C" void kernel_launch(void* const* d_in, const int* in_sizes, int n_in,
                              void* d_out, int out_size, void* d_ws,
                              size_t ws_size, hipStream_t stream) {
  const float* x      = (const float*)d_in[0];
  const float* p      = (const float*)d_in[1];
  const float* a_uc   = (const float*)d_in[2];
  const float* b_uc   = (const float*)d_in[3];
  const float* u_pi   = (const float*)d_in[4];
  const float* u_rb   = (const float*)d_in[5];
  const float* lin_w  = (const float*)d_in[6];
  const float* lin_b  = (const float*)d_in[7];
  const float* fc_w   = (const float*)d_in[8];
  const float* fc_b   = (const float*)d_in[9];
  // d_in[10] edge_index, d_in[11] batch: fully deterministic, never read.
  float* out = (float*)d_out;
  float* ws  = (float*)d_ws;

  build_all<<<256, 256, 0, stream>>>(p, u_rb, a_uc, b_uc, u_pi, ws, out);
  batch_chain<<<64, 1024, 0, stream>>>(x, ws, lin_w, lin_b, fc_w, fc_b, out);
}